// Round 2
// baseline (10095.744 us; speedup 1.0000x reference)
//
#include <hip/hip_runtime.h>

// Problem sizes
#define SEQ   512
#define NB    32
#define NH    512
#define BH    16384       // NB*NH
#define EPSF  1e-7f
#define NWG   64          // workgroups in persistent recurrent kernel

// d_out offsets (float elements): out(S,B,O), h_f(1,B,H), c_f(1,B,H), mem_f(513,B,H)
#define HF_OFF  8388608
#define CF_OFF  8404992
#define MEM_OFF 8421376

// ws offsets (bytes)
#define X0_OFF   0u           // u16 [512][32][512]  bf16 hi of x
#define X1_OFF   16777216u    // u16 mid
#define X2_OFF   33554432u    // u16 lo
#define WI0_OFF  50331648u    // u16 [2048][512] w_ih hi
#define WI1_OFF  52428800u    // mid
#define WI2_OFF  54525952u    // lo
#define HH_OFF   56623104u    // u16 [513][32][512]  h hi (slot0=h0, slot t+1=h_out_t)
#define HM_OFF   73433088u    // u16 [2][32][512]    h mid ring
#define HL_OFF   73498624u    // u16 [2][32][512]    h lo ring
#define MSEQ_OFF 73564160u    // u16 [512][32][512]  bf16(m_t)
#define FCW_OFF  90341376u    // u16 [512][1024]     bf16(fc_w)
#define S2P_OFF  91389952u    // f32 [2][32][64]     per-WG score partials (double buffered)
#define BAR_OFF  91406336u    // u32 [64]            barrier slots
#define GX_OFF   91406592u    // f32 [512*32][2048]  precomputed x@w_ih^T + b_ih + b_hh (134 MB)

typedef __attribute__((ext_vector_type(8))) short bf16x8;
typedef __attribute__((ext_vector_type(4))) float f32x4;

__device__ __forceinline__ unsigned short f2bf(float f){
  unsigned u = __float_as_uint(f);
  unsigned r = (u + 0x7fffu + ((u >> 16) & 1u)) >> 16;   // RNE
  return (unsigned short)r;
}
__device__ __forceinline__ float bf2f(unsigned short h){
  return __uint_as_float(((unsigned)h) << 16);
}
__device__ __forceinline__ float sigmf(float x){ return 1.f/(1.f + __expf(-x)); }
__device__ __forceinline__ float tanhff(float x){
  x = fminf(20.f, fmaxf(-20.f, x));
  float e = __expf(-2.f*x);
  return (1.f - e)/(1.f + e);
}

// flat device-scope barrier over NWG workgroups; each WG owns one slot.
__device__ __forceinline__ void gbar(unsigned* bar, int g, unsigned epoch){
  __syncthreads();
  if (threadIdx.x == 0){
    __threadfence();                     // release
    __hip_atomic_store(&bar[g], epoch, __ATOMIC_RELAXED, __HIP_MEMORY_SCOPE_AGENT);
  }
  if (threadIdx.x < 64){
    while (true){
      unsigned v = __hip_atomic_load(&bar[threadIdx.x], __ATOMIC_RELAXED, __HIP_MEMORY_SCOPE_AGENT);
      if (__all((int)(v >= epoch))) break;
    }
  }
  __syncthreads();
  __threadfence();                       // acquire
}

// ---------------- phase 0: exact 3-way bf16 splits + init (zeroes barrier every launch)
__global__ void phase0(const float* __restrict__ x, const float* __restrict__ h0,
                       const float* __restrict__ mem0, const float* __restrict__ fcw,
                       const float* __restrict__ wih,
                       unsigned short* __restrict__ x0, unsigned short* __restrict__ x1,
                       unsigned short* __restrict__ x2,
                       unsigned short* __restrict__ wi0, unsigned short* __restrict__ wi1,
                       unsigned short* __restrict__ wi2,
                       unsigned short* __restrict__ hh, unsigned short* __restrict__ hm,
                       unsigned short* __restrict__ hl,
                       unsigned short* __restrict__ fcwb,
                       float* __restrict__ mem_row0, unsigned* __restrict__ bar){
  long i = (long)blockIdx.x * blockDim.x + threadIdx.x;
  if (i < (long)SEQ*BH){
    float v = x[i];
    unsigned short a = f2bf(v); float r = v - bf2f(a);
    unsigned short b = f2bf(r); float r2 = r - bf2f(b);
    x0[i]=a; x1[i]=b; x2[i]=f2bf(r2);
  }
  if (i < 2048*512){
    float v = wih[i];
    unsigned short a = f2bf(v); float r = v - bf2f(a);
    unsigned short b = f2bf(r); float r2 = r - bf2f(b);
    wi0[i]=a; wi1[i]=b; wi2[i]=f2bf(r2);
  }
  if (i < 512*1024) fcwb[i] = f2bf(fcw[i]);
  if (i < BH){
    float h = h0[i];
    unsigned short a = f2bf(h); float r = h - bf2f(a);
    unsigned short b = f2bf(r); float r2 = r - bf2f(b);
    hh[i]=a; hm[i]=b; hl[i]=f2bf(r2);
    mem_row0[i] = mem0[i];
  }
  if (i < NWG) bar[i] = 0u;
}

// ---------------- phase 1: G_x = x @ w_ih^T + b_ih + b_hh  (fp32-quality via 6-term split MFMA)
// M=16384 (row = t*32+b), N=2048, K=512
__launch_bounds__(256)
__global__ void xgemm(const unsigned short* __restrict__ x0, const unsigned short* __restrict__ x1,
                      const unsigned short* __restrict__ x2,
                      const unsigned short* __restrict__ wi0, const unsigned short* __restrict__ wi1,
                      const unsigned short* __restrict__ wi2,
                      const float* __restrict__ bih, const float* __restrict__ bhh,
                      float* __restrict__ gx){
  const int tid = threadIdx.x;
  const int wave = tid >> 6, lane = tid & 63, quad = lane >> 4, ln = lane & 15;
  const int rowb = blockIdx.x*64 + wave*16;     // 16-row strip per wave
  const int colb = blockIdx.y*64;               // 64-col strip per WG
  const long aoff = (long)(rowb + ln)*512 + quad*8;
  f32x4 acc[4] = {{0,0,0,0},{0,0,0,0},{0,0,0,0},{0,0,0,0}};
  #pragma unroll 4
  for (int ki = 0; ki < 16; ++ki){
    bf16x8 a0 = *(const bf16x8*)(x0 + aoff + ki*32);
    bf16x8 a1 = *(const bf16x8*)(x1 + aoff + ki*32);
    bf16x8 a2 = *(const bf16x8*)(x2 + aoff + ki*32);
    #pragma unroll
    for (int n = 0; n < 4; ++n){
      long bo = (long)(colb + n*16 + ln)*512 + quad*8 + ki*32;
      bf16x8 b0 = *(const bf16x8*)(wi0 + bo);
      bf16x8 b1 = *(const bf16x8*)(wi1 + bo);
      bf16x8 b2 = *(const bf16x8*)(wi2 + bo);
      acc[n] = __builtin_amdgcn_mfma_f32_16x16x32_bf16(a0, b0, acc[n], 0,0,0);
      acc[n] = __builtin_amdgcn_mfma_f32_16x16x32_bf16(a0, b1, acc[n], 0,0,0);
      acc[n] = __builtin_amdgcn_mfma_f32_16x16x32_bf16(a1, b0, acc[n], 0,0,0);
      acc[n] = __builtin_amdgcn_mfma_f32_16x16x32_bf16(a0, b2, acc[n], 0,0,0);
      acc[n] = __builtin_amdgcn_mfma_f32_16x16x32_bf16(a2, b0, acc[n], 0,0,0);
      acc[n] = __builtin_amdgcn_mfma_f32_16x16x32_bf16(a1, b1, acc[n], 0,0,0);
    }
  }
  #pragma unroll
  for (int n = 0; n < 4; ++n){
    int col = colb + n*16 + ln;
    float bias = bih[col] + bhh[col];
    #pragma unroll
    for (int rr = 0; rr < 4; ++rr){
      int row = rowb + quad*4 + rr;              // C/D: row=quad*4+reg, col=lane&15
      gx[(long)row*2048 + col] = acc[n][rr] + bias;
    }
  }
}

// ---------------- phase 2: persistent recurrent kernel: 64 WGs x 256 threads
__launch_bounds__(256, 1)
__global__ void recurrent(const unsigned short* __restrict__ hh_,
                          unsigned short* __restrict__ hm,
                          unsigned short* __restrict__ hl,
                          unsigned short* __restrict__ mseq,
                          float* __restrict__ s2p,
                          unsigned* __restrict__ bar,
                          float* __restrict__ dout,
                          const float* __restrict__ gx,
                          const float* __restrict__ whh,
                          const float* __restrict__ wt,
                          const float* __restrict__ c0){
  unsigned short* hh = (unsigned short*)hh_;
  const int g    = blockIdx.x;           // WG owns hidden cols [g*8, g*8+8), all 4 gates
  const int tid  = threadIdx.x;
  const int wave = tid >> 6, lane = tid & 63, quad = lane >> 4, ln = lane & 15;
  const int mtile = wave & 1, ntile = wave >> 1;   // 32x32 tile = 2x2 of 16x16 per wave

  __shared__ float gates_lds[32*33];     // [b][c], padded
  __shared__ float wt_lds[32*5];
  __shared__ int   idx_lds[32*5];

  // w_hh 3-split fragments in registers (exact 24-bit decomposition)
  bf16x8 fW0[16], fW1[16], fW2[16];
  {
    int cl   = ntile*16 + ln;            // local col 0..31; c = gate*8 + jloc
    int gate = cl >> 3, jl = cl & 7;
    long grow = (long)(gate*NH + g*8 + jl);
    const float* wh = whh + grow*NH;
    #pragma unroll
    for (int ki = 0; ki < 16; ++ki){
      int k0 = ki*32 + quad*8;
      bf16x8 a, b, c;
      #pragma unroll
      for (int e = 0; e < 8; ++e){
        float vh = wh[k0+e];
        unsigned short w0 = f2bf(vh); float r = vh - bf2f(w0);
        unsigned short w1 = f2bf(r);  float r2 = r - bf2f(w1);
        a[e] = (short)w0; b[e] = (short)w1; c[e] = (short)f2bf(r2);
      }
      fW0[ki]=a; fW1[ki]=b; fW2[ki]=c;
    }
  }

  // elementwise ownership: thread <-> (b, jloc)
  const int b_  = tid >> 3, jl_ = tid & 7;
  const int jg_ = g*8 + jl_;
  const float wt2 = wt[NH + jg_];        // memory half of w_t (h half cancels)
  float creg = c0[b_*NH + jg_];
  float* memf = dout + MEM_OFF;

  // s2 partial for entry 0 (= mem0, copied to mem row 0 by phase0)
  {
    float v = tanhff(memf[b_*NH + jg_]) * wt2;
    v += __shfl_xor(v, 1); v += __shfl_xor(v, 2); v += __shfl_xor(v, 4);
    if (jl_ == 0) s2p[b_*64 + g] = v;    // parity slot 0
  }

  // replicated incremental top-5 (wave0 lanes 0..31, lane = batch)
  float tv0=-3e38f,tv1=-3e38f,tv2=-3e38f,tv3=-3e38f,tv4=-3e38f;
  int   ti0=0,ti1=0,ti2=0,ti3=0,ti4=0;

  unsigned epoch = 1u;
  gbar(bar, g, epoch);                   // entry-0 partials visible everywhere

  const long arow = (long)(mtile*16 + ln)*NH + quad*8;   // A-frag element offset

  #pragma unroll 1
  for (int t = 0; t < SEQ; ++t){
    // --- gates tile: h_t @ w_hh^T via 6-term split MFMA (fp32-quality)
    f32x4 acc = {0.f,0.f,0.f,0.f};
    const unsigned short* p0 = hh + (long)t*BH + arow;
    const unsigned short* p1 = hm + (long)(t&1)*BH + arow;
    const unsigned short* p2 = hl + (long)(t&1)*BH + arow;
    #pragma unroll
    for (int ki = 0; ki < 16; ++ki){
      bf16x8 a0 = *(const bf16x8*)(p0 + ki*32);
      bf16x8 a1 = *(const bf16x8*)(p1 + ki*32);
      bf16x8 a2 = *(const bf16x8*)(p2 + ki*32);
      acc = __builtin_amdgcn_mfma_f32_16x16x32_bf16(a0, fW0[ki], acc, 0,0,0);
      acc = __builtin_amdgcn_mfma_f32_16x16x32_bf16(a0, fW1[ki], acc, 0,0,0);
      acc = __builtin_amdgcn_mfma_f32_16x16x32_bf16(a1, fW0[ki], acc, 0,0,0);
      acc = __builtin_amdgcn_mfma_f32_16x16x32_bf16(a0, fW2[ki], acc, 0,0,0);
      acc = __builtin_amdgcn_mfma_f32_16x16x32_bf16(a2, fW0[ki], acc, 0,0,0);
      acc = __builtin_amdgcn_mfma_f32_16x16x32_bf16(a1, fW1[ki], acc, 0,0,0);
    }
    #pragma unroll
    for (int r = 0; r < 4; ++r){
      int brow = mtile*16 + quad*4 + r;          // C/D: row=quad*4+reg, col=lane&15
      gates_lds[brow*33 + ntile*16 + ln] = acc[r];
    }

    // --- wave0: finalize entry-t score, insert into top-5, emit sparse weights
    if (tid < 32){
      const float* sp = s2p + (t&1)*2048 + tid*64;
      float s = 0.f;
      #pragma unroll
      for (int q = 0; q < 16; ++q){
        float4 v4 = *(const float4*)(sp + q*4);
        s += v4.x + v4.y + v4.z + v4.w;          // fixed order → bit-identical across WGs
      }
      if (t < 5){
        if      (t==0){tv0=s;ti0=0;}
        else if (t==1){tv1=s;ti1=1;}
        else if (t==2){tv2=s;ti2=2;}
        else if (t==3){tv3=s;ti3=3;}
        else          {tv4=s;ti4=4;}
      } else {
        float mn = fminf(fminf(fminf(tv0,tv1),fminf(tv2,tv3)),tv4);
        if (s > mn){
          if      (tv0==mn){tv0=s;ti0=t;}
          else if (tv1==mn){tv1=s;ti1=t;}
          else if (tv2==mn){tv2=s;ti2=t;}
          else if (tv3==mn){tv3=s;ti3=t;}
          else             {tv4=s;ti4=t;}
        }
      }
      int cnt = (t+1 < 5) ? (t+1) : 5;
      float mn = tv0;
      if (cnt>1) mn = fminf(mn, tv1);
      if (cnt>2) mn = fminf(mn, tv2);
      if (cnt>3) mn = fminf(mn, tv3);
      if (cnt>4) mn = fminf(mn, tv4);
      float thr = mn + EPSF;                     // kth/min + eps; h-term cancels
      float w0 =            fmaxf(tv0-thr,0.f);
      float w1 = (cnt>1) ? fmaxf(tv1-thr,0.f) : 0.f;
      float w2 = (cnt>2) ? fmaxf(tv2-thr,0.f) : 0.f;
      float w3 = (cnt>3) ? fmaxf(tv3-thr,0.f) : 0.f;
      float w4 = (cnt>4) ? fmaxf(tv4-thr,0.f) : 0.f;
      float inv = 1.f/((w0+w1+w2+w3+w4) + EPSF);
      wt_lds[tid*5+0]=w0*inv; idx_lds[tid*5+0]=ti0;
      wt_lds[tid*5+1]=w1*inv; idx_lds[tid*5+1]=ti1;
      wt_lds[tid*5+2]=w2*inv; idx_lds[tid*5+2]=ti2;
      wt_lds[tid*5+3]=w3*inv; idx_lds[tid*5+3]=ti3;
      wt_lds[tid*5+4]=w4*inv; idx_lds[tid*5+4]=ti4;
    }
    __syncthreads();

    // --- LSTM elementwise (gates = G_x[t] + h-path) + sparse gather + append
    const float* gxr = gx + (long)(t*32 + b_)*2048;
    float g0 = gates_lds[b_*33 + jl_     ] + gxr[jg_];          // i
    float g1 = gates_lds[b_*33 +  8 + jl_] + gxr[NH + jg_];     // f
    float g2 = gates_lds[b_*33 + 16 + jl_] + gxr[2*NH + jg_];   // g
    float g3 = gates_lds[b_*33 + 24 + jl_] + gxr[3*NH + jg_];   // o
    float ig = sigmf(g0), fg = sigmf(g1), gg = tanhff(g2), og = sigmf(g3);
    creg = fg*creg + ig*gg;
    float hn = og * tanhff(creg);
    float mt = 0.f;
    #pragma unroll
    for (int l = 0; l < 5; ++l){
      float w = wt_lds[b_*5 + l];
      int  id = idx_lds[b_*5 + l];
      mt += w * memf[(long)id*BH + b_*NH + jg_];
    }
    float ho = hn + mt;
    long eoff = (long)b_*NH + jg_;
    memf[(long)(t+1)*BH + eoff] = ho;               // mem append == h_seq
    unsigned short h0s = f2bf(ho); float r = ho - bf2f(h0s);
    unsigned short h1s = f2bf(r);  float r2 = r - bf2f(h1s);
    hh[(long)(t+1)*BH + eoff] = h0s;
    hm[(long)((t+1)&1)*BH + eoff] = h1s;
    hl[(long)((t+1)&1)*BH + eoff] = f2bf(r2);
    mseq[(long)t*BH + eoff] = f2bf(mt);
    if (t == SEQ-1) dout[HF_OFF + eoff] = ho;       // h_f

    // s2 partial of the appended entry (t+1)
    float v = tanhff(ho) * wt2;
    v += __shfl_xor(v, 1); v += __shfl_xor(v, 2); v += __shfl_xor(v, 4);
    if (jl_ == 0) s2p[((t+1)&1)*2048 + b_*64 + g] = v;

    ++epoch;
    gbar(bar, g, epoch);
  }
  dout[CF_OFF + (long)b_*NH + jg_] = creg;          // c_f
}

// ---------------- phase 3: out = [h_seq; m_seq] @ fc_w^T + fc_b   (M=16384, N=512, K=1024)
__launch_bounds__(256)
__global__ void outgemm(const unsigned short* __restrict__ hh,
                        const unsigned short* __restrict__ mseq,
                        const unsigned short* __restrict__ fcwb,
                        const float* __restrict__ fcb,
                        float* __restrict__ out){
  const int tid = threadIdx.x;
  const int wave = tid >> 6, lane = tid & 63, quad = lane >> 4, ln = lane & 15;
  const int wgM = blockIdx.x;            // 256 tiles of 64 rows
  const int wgN = blockIdx.y;            // 8 tiles of 64 cols
  const int r = wgM*64 + wave*16 + ln;   // row (s*32+b); 16-row tiles never straddle s
  const int s = r >> 5, b = r & 31;
  const unsigned short* pa_h = hh   + (long)(s+1)*BH + (long)b*NH + quad*8;  // h_seq[s] = slot s+1
  const unsigned short* pa_m = mseq + (long)s*BH     + (long)b*NH + quad*8;
  const unsigned short* pb   = fcwb + (long)(wgN*64 + ln)*1024 + quad*8;
  f32x4 accs[4] = {{0,0,0,0},{0,0,0,0},{0,0,0,0},{0,0,0,0}};
  #pragma unroll 4
  for (int ki = 0; ki < 16; ++ki){       // h half (k < 512)
    bf16x8 a = *(const bf16x8*)(pa_h + ki*32);
    #pragma unroll
    for (int n = 0; n < 4; ++n){
      bf16x8 bb = *(const bf16x8*)(pb + (long)n*16*1024 + ki*32);
      accs[n] = __builtin_amdgcn_mfma_f32_16x16x32_bf16(a, bb, accs[n], 0,0,0);
    }
  }
  #pragma unroll 4
  for (int ki = 0; ki < 16; ++ki){       // m half (k >= 512)
    bf16x8 a = *(const bf16x8*)(pa_m + ki*32);
    #pragma unroll
    for (int n = 0; n < 4; ++n){
      bf16x8 bb = *(const bf16x8*)(pb + 512 + (long)n*16*1024 + ki*32);
      accs[n] = __builtin_amdgcn_mfma_f32_16x16x32_bf16(a, bb, accs[n], 0,0,0);
    }
  }
  #pragma unroll
  for (int n = 0; n < 4; ++n){
    int o = wgN*64 + n*16 + ln;
    float bias = fcb[o];
    #pragma unroll
    for (int rr = 0; rr < 4; ++rr){
      int row = wgM*64 + wave*16 + quad*4 + rr;
      out[(long)row*512 + o] = accs[n][rr] + bias;
    }
  }
}

extern "C" void kernel_launch(void* const* d_in, const int* in_sizes, int n_in,
                              void* d_out, int out_size, void* d_ws, size_t ws_size,
                              hipStream_t stream){
  (void)in_sizes; (void)n_in; (void)out_size; (void)ws_size;
  const float* x    = (const float*)d_in[0];
  const float* h0   = (const float*)d_in[1];
  const float* c0   = (const float*)d_in[2];
  const float* mem0 = (const float*)d_in[3];
  const float* wih  = (const float*)d_in[4];
  const float* whh  = (const float*)d_in[5];
  const float* bih  = (const float*)d_in[6];
  const float* bhh  = (const float*)d_in[7];
  const float* wt   = (const float*)d_in[8];
  const float* fcw  = (const float*)d_in[9];
  const float* fcb  = (const float*)d_in[10];
  float* out = (float*)d_out;
  char* ws = (char*)d_ws;

  unsigned short* x0   = (unsigned short*)(ws + X0_OFF);
  unsigned short* x1   = (unsigned short*)(ws + X1_OFF);
  unsigned short* x2   = (unsigned short*)(ws + X2_OFF);
  unsigned short* wi0  = (unsigned short*)(ws + WI0_OFF);
  unsigned short* wi1  = (unsigned short*)(ws + WI1_OFF);
  unsigned short* wi2  = (unsigned short*)(ws + WI2_OFF);
  unsigned short* hh   = (unsigned short*)(ws + HH_OFF);
  unsigned short* hm   = (unsigned short*)(ws + HM_OFF);
  unsigned short* hl   = (unsigned short*)(ws + HL_OFF);
  unsigned short* mseq = (unsigned short*)(ws + MSEQ_OFF);
  unsigned short* fcwb = (unsigned short*)(ws + FCW_OFF);
  float*          s2p  = (float*)(ws + S2P_OFF);
  unsigned*       bar  = (unsigned*)(ws + BAR_OFF);
  float*          gx   = (float*)(ws + GX_OFF);

  phase0<<<32768, 256, 0, stream>>>(x, h0, mem0, fcw, wih,
                                    x0, x1, x2, wi0, wi1, wi2,
                                    hh, hm, hl, fcwb, out + MEM_OFF, bar);
  xgemm<<<dim3(256, 32), 256, 0, stream>>>(x0, x1, x2, wi0, wi1, wi2, bih, bhh, gx);
  recurrent<<<NWG, 256, 0, stream>>>(hh, hm, hl, mseq, s2p, bar, out,
                                     gx, whh, wt, c0);
  outgemm<<<dim3(256, 8), 256, 0, stream>>>(hh, mseq, fcwb, fcb, out);
}

// Round 3
// 5796.498 us; speedup vs baseline: 1.7417x; 1.7417x over previous
//
#include <hip/hip_runtime.h>

// Problem sizes
#define SEQ   512
#define NB    32
#define NH    512
#define BH    16384       // NB*NH
#define EPSF  1e-7f
#define NWG   64          // workgroups in persistent recurrent kernel

// d_out offsets (float elements): out(S,B,O), h_f(1,B,H), c_f(1,B,H), mem_f(513,B,H)
#define HF_OFF  8388608
#define CF_OFF  8404992
#define MEM_OFF 8421376

// ws offsets (bytes)
#define X0_OFF   0u           // u16 [512][32][512]  bf16 hi of x
#define X1_OFF   16777216u    // u16 mid of x
#define WI0_OFF  33554432u    // u16 [2048][512] w_ih hi
#define WI1_OFF  35651584u    // u16 mid
#define HH_OFF   37748736u    // u16 [513][32][512]  h hi  (slot0=h0, slot t+1=h_out_t)
#define HMF_OFF  54558720u    // u16 [513][32][512]  h mid (full-size: write-once per launch)
#define MSEQ_OFF 71368704u    // u16 [512][32][512]  bf16(m_t)
#define FCW_OFF  88145920u    // u16 [512][1024]     bf16(fc_w)
#define S2P_OFF  89194496u    // f32 [513][32][64]   per-WG score partials (write-once slots)
#define BAR_OFF  93396992u    // u32 [64]            barrier slots
#define GX_OFF   93397248u    // f32 [512*32][2048]  precomputed x@w_ih^T + b_ih + b_hh

typedef __attribute__((ext_vector_type(8))) short bf16x8;
typedef __attribute__((ext_vector_type(4))) float f32x4;

__device__ __forceinline__ unsigned short f2bf(float f){
  unsigned u = __float_as_uint(f);
  unsigned r = (u + 0x7fffu + ((u >> 16) & 1u)) >> 16;   // RNE
  return (unsigned short)r;
}
__device__ __forceinline__ float bf2f(unsigned short h){
  return __uint_as_float(((unsigned)h) << 16);
}
__device__ __forceinline__ float sigmf(float x){ return 1.f/(1.f + __expf(-x)); }
__device__ __forceinline__ float tanhff(float x){
  x = fminf(20.f, fmaxf(-20.f, x));
  float e = __expf(-2.f*x);
  return (1.f - e)/(1.f + e);
}

// Fence-free flat device barrier: all cross-WG data is written via agent-scope
// relaxed atomic stores (sc0 sc1 write-through to LLC); __syncthreads' vmcnt(0)
// guarantees those stores are acked before the bar store issues. No buffer_wbl2 /
// buffer_inv anywhere.
__device__ __forceinline__ void gbar(unsigned* bar, int g, unsigned epoch){
  __syncthreads();                       // s_waitcnt vmcnt(0) + s_barrier
  if (threadIdx.x == 0)
    __hip_atomic_store(&bar[g], epoch, __ATOMIC_RELAXED, __HIP_MEMORY_SCOPE_AGENT);
  if (threadIdx.x < 64){
    while (true){
      unsigned v = __hip_atomic_load(&bar[threadIdx.x], __ATOMIC_RELAXED, __HIP_MEMORY_SCOPE_AGENT);
      if (__all((int)(v >= epoch))) break;
    }
  }
  __syncthreads();                       // also a compiler memory barrier
}

// ---------------- phase 0: 2-way bf16 splits + init (zeroes barrier every launch)
__global__ void phase0(const float* __restrict__ x, const float* __restrict__ h0,
                       const float* __restrict__ mem0, const float* __restrict__ fcw,
                       const float* __restrict__ wih,
                       unsigned short* __restrict__ x0, unsigned short* __restrict__ x1,
                       unsigned short* __restrict__ wi0, unsigned short* __restrict__ wi1,
                       unsigned short* __restrict__ hh, unsigned short* __restrict__ hmf,
                       unsigned short* __restrict__ fcwb,
                       float* __restrict__ mem_row0, unsigned* __restrict__ bar){
  long i = (long)blockIdx.x * blockDim.x + threadIdx.x;
  if (i < (long)SEQ*BH){
    float v = x[i];
    unsigned short a = f2bf(v);
    x0[i]=a; x1[i]=f2bf(v - bf2f(a));
  }
  if (i < 2048*512){
    float v = wih[i];
    unsigned short a = f2bf(v);
    wi0[i]=a; wi1[i]=f2bf(v - bf2f(a));
  }
  if (i < 512*1024) fcwb[i] = f2bf(fcw[i]);
  if (i < BH){
    float h = h0[i];
    unsigned short a = f2bf(h);
    hh[i]=a; hmf[i]=f2bf(h - bf2f(a));
    mem_row0[i] = mem0[i];
  }
  if (i < NWG) bar[i] = 0u;
}

// ---------------- phase 1: G_x = x @ w_ih^T + b_ih + b_hh  (4-term split MFMA, ~2^-17 rel)
// M=16384 (row = t*32+b), N=2048, K=512
__launch_bounds__(256)
__global__ void xgemm(const unsigned short* __restrict__ x0, const unsigned short* __restrict__ x1,
                      const unsigned short* __restrict__ wi0, const unsigned short* __restrict__ wi1,
                      const float* __restrict__ bih, const float* __restrict__ bhh,
                      float* __restrict__ gx){
  const int tid = threadIdx.x;
  const int wave = tid >> 6, lane = tid & 63, quad = lane >> 4, ln = lane & 15;
  const int rowb = blockIdx.x*64 + wave*16;
  const int colb = blockIdx.y*64;
  const long aoff = (long)(rowb + ln)*512 + quad*8;
  f32x4 acc[4] = {{0,0,0,0},{0,0,0,0},{0,0,0,0},{0,0,0,0}};
  #pragma unroll 4
  for (int ki = 0; ki < 16; ++ki){
    bf16x8 a0 = *(const bf16x8*)(x0 + aoff + ki*32);
    bf16x8 a1 = *(const bf16x8*)(x1 + aoff + ki*32);
    #pragma unroll
    for (int n = 0; n < 4; ++n){
      long bo = (long)(colb + n*16 + ln)*512 + quad*8 + ki*32;
      bf16x8 b0 = *(const bf16x8*)(wi0 + bo);
      bf16x8 b1 = *(const bf16x8*)(wi1 + bo);
      acc[n] = __builtin_amdgcn_mfma_f32_16x16x32_bf16(a0, b0, acc[n], 0,0,0);
      acc[n] = __builtin_amdgcn_mfma_f32_16x16x32_bf16(a0, b1, acc[n], 0,0,0);
      acc[n] = __builtin_amdgcn_mfma_f32_16x16x32_bf16(a1, b0, acc[n], 0,0,0);
      acc[n] = __builtin_amdgcn_mfma_f32_16x16x32_bf16(a1, b1, acc[n], 0,0,0);
    }
  }
  #pragma unroll
  for (int n = 0; n < 4; ++n){
    int col = colb + n*16 + ln;
    float bias = bih[col] + bhh[col];
    #pragma unroll
    for (int rr = 0; rr < 4; ++rr){
      int row = rowb + quad*4 + rr;
      gx[(long)row*2048 + col] = acc[n][rr] + bias;
    }
  }
}

// ---------------- phase 2: persistent recurrent kernel: 64 WGs x 256 threads
__launch_bounds__(256, 1)
__global__ void recurrent(unsigned short* __restrict__ hh,
                          unsigned short* __restrict__ hmf,
                          unsigned short* __restrict__ mseq,
                          float* __restrict__ s2p,
                          unsigned* __restrict__ bar,
                          float* __restrict__ dout,
                          const float* __restrict__ gx,
                          const float* __restrict__ whh,
                          const float* __restrict__ wt,
                          const float* __restrict__ c0){
  const int g    = blockIdx.x;           // WG owns hidden cols [g*8, g*8+8), all 4 gates
  const int tid  = threadIdx.x;
  const int wave = tid >> 6, lane = tid & 63, quad = lane >> 4, ln = lane & 15;
  const int mtile = wave & 1, ntile = wave >> 1;   // 32x32 tile = 2x2 of 16x16 per wave

  __shared__ float gates_lds[32*33];     // [b][c], padded
  __shared__ float wt_lds[32*5];
  __shared__ int   idx_lds[32*5];

  // w_hh 2-split fragments in registers (hi+mid, 3-term scheme)
  bf16x8 fW0[16], fW1[16];
  {
    int cl   = ntile*16 + ln;            // local col 0..31; c = gate*8 + jloc
    int gate = cl >> 3, jl = cl & 7;
    long grow = (long)(gate*NH + g*8 + jl);
    const float* wh = whh + grow*NH;
    #pragma unroll
    for (int ki = 0; ki < 16; ++ki){
      int k0 = ki*32 + quad*8;
      bf16x8 a, b;
      #pragma unroll
      for (int e = 0; e < 8; ++e){
        float vh = wh[k0+e];
        unsigned short w0 = f2bf(vh);
        a[e] = (short)w0; b[e] = (short)f2bf(vh - bf2f(w0));
      }
      fW0[ki]=a; fW1[ki]=b;
    }
  }

  // elementwise ownership: thread <-> (b, jloc)
  const int b_  = tid >> 3, jl_ = tid & 7;
  const int jg_ = g*8 + jl_;
  const float wt2 = wt[NH + jg_];        // memory half of w_t (h half cancels)
  float creg = c0[b_*NH + jg_];
  float* memf = dout + MEM_OFF;

  // s2 partial for entry 0 (= mem0, copied to mem row 0 by phase0)
  {
    float v = tanhff(memf[b_*NH + jg_]) * wt2;
    v += __shfl_xor(v, 1); v += __shfl_xor(v, 2); v += __shfl_xor(v, 4);
    if (jl_ == 0)
      __hip_atomic_store((unsigned*)(s2p + b_*64 + g), __float_as_uint(v),
                         __ATOMIC_RELAXED, __HIP_MEMORY_SCOPE_AGENT);
  }

  // replicated incremental top-5 (wave0 lanes 0..31, lane = batch)
  float tv0=-3e38f,tv1=-3e38f,tv2=-3e38f,tv3=-3e38f,tv4=-3e38f;
  int   ti0=0,ti1=0,ti2=0,ti3=0,ti4=0;

  unsigned epoch = 1u;
  gbar(bar, g, epoch);                   // entry-0 partials at LLC, visible everywhere

  const long arow = (long)(mtile*16 + ln)*NH + quad*8;   // A-frag element offset

  #pragma unroll 1
  for (int t = 0; t < SEQ; ++t){
    // --- prefetches (independent of MFMA chain): gx row + s2p slot t
    const float* gxr = gx + ((long)t*32 + b_)*2048 + jg_;
    float gxi = gxr[0], gxf = gxr[512], gxg = gxr[1024], gxo = gxr[1536];
    float4 sv[16];
    if (tid < 32){
      const float4* sp = (const float4*)(s2p + (long)t*2048 + tid*64);
      #pragma unroll
      for (int q = 0; q < 16; ++q) sv[q] = sp[q];
    }

    // --- gates tile: h_t @ w_hh^T, 3-term split MFMA, two independent chains
    const unsigned short* p0 = hh  + (long)t*BH + arow;
    const unsigned short* p1 = hmf + (long)t*BH + arow;
    f32x4 acc0 = {0.f,0.f,0.f,0.f}, acc1 = {0.f,0.f,0.f,0.f};
    #pragma unroll
    for (int ki = 0; ki < 16; ki += 2){
      bf16x8 aH0 = *(const bf16x8*)(p0 + ki*32);
      bf16x8 aM0 = *(const bf16x8*)(p1 + ki*32);
      bf16x8 aH1 = *(const bf16x8*)(p0 + ki*32 + 32);
      bf16x8 aM1 = *(const bf16x8*)(p1 + ki*32 + 32);
      acc0 = __builtin_amdgcn_mfma_f32_16x16x32_bf16(aH0, fW0[ki],   acc0, 0,0,0);
      acc1 = __builtin_amdgcn_mfma_f32_16x16x32_bf16(aH1, fW0[ki+1], acc1, 0,0,0);
      acc0 = __builtin_amdgcn_mfma_f32_16x16x32_bf16(aH0, fW1[ki],   acc0, 0,0,0);
      acc1 = __builtin_amdgcn_mfma_f32_16x16x32_bf16(aH1, fW1[ki+1], acc1, 0,0,0);
      acc0 = __builtin_amdgcn_mfma_f32_16x16x32_bf16(aM0, fW0[ki],   acc0, 0,0,0);
      acc1 = __builtin_amdgcn_mfma_f32_16x16x32_bf16(aM1, fW0[ki+1], acc1, 0,0,0);
    }
    #pragma unroll
    for (int r = 0; r < 4; ++r){
      int brow = mtile*16 + quad*4 + r;          // C/D: row=quad*4+reg, col=lane&15
      gates_lds[brow*33 + ntile*16 + ln] = acc0[r] + acc1[r];
    }

    // --- wave0: finalize entry-t score, insert into top-5, emit sparse weights
    if (tid < 32){
      float s = 0.f;
      #pragma unroll
      for (int q = 0; q < 16; ++q){
        s += sv[q].x + sv[q].y + sv[q].z + sv[q].w;  // fixed order → bit-identical across WGs
      }
      if (t < 5){
        if      (t==0){tv0=s;ti0=0;}
        else if (t==1){tv1=s;ti1=1;}
        else if (t==2){tv2=s;ti2=2;}
        else if (t==3){tv3=s;ti3=3;}
        else          {tv4=s;ti4=4;}
      } else {
        float mn = fminf(fminf(fminf(tv0,tv1),fminf(tv2,tv3)),tv4);
        if (s > mn){
          if      (tv0==mn){tv0=s;ti0=t;}
          else if (tv1==mn){tv1=s;ti1=t;}
          else if (tv2==mn){tv2=s;ti2=t;}
          else if (tv3==mn){tv3=s;ti3=t;}
          else             {tv4=s;ti4=t;}
        }
      }
      int cnt = (t+1 < 5) ? (t+1) : 5;
      float mn = tv0;
      if (cnt>1) mn = fminf(mn, tv1);
      if (cnt>2) mn = fminf(mn, tv2);
      if (cnt>3) mn = fminf(mn, tv3);
      if (cnt>4) mn = fminf(mn, tv4);
      float thr = mn + EPSF;                     // kth/min + eps; h-term cancels
      float w0 =            fmaxf(tv0-thr,0.f);
      float w1 = (cnt>1) ? fmaxf(tv1-thr,0.f) : 0.f;
      float w2 = (cnt>2) ? fmaxf(tv2-thr,0.f) : 0.f;
      float w3 = (cnt>3) ? fmaxf(tv3-thr,0.f) : 0.f;
      float w4 = (cnt>4) ? fmaxf(tv4-thr,0.f) : 0.f;
      float inv = 1.f/((w0+w1+w2+w3+w4) + EPSF);
      wt_lds[tid*5+0]=w0*inv; idx_lds[tid*5+0]=ti0;
      wt_lds[tid*5+1]=w1*inv; idx_lds[tid*5+1]=ti1;
      wt_lds[tid*5+2]=w2*inv; idx_lds[tid*5+2]=ti2;
      wt_lds[tid*5+3]=w3*inv; idx_lds[tid*5+3]=ti3;
      wt_lds[tid*5+4]=w4*inv; idx_lds[tid*5+4]=ti4;
    }
    __syncthreads();

    // --- LSTM elementwise (gates = G_x[t] + h-path) + sparse gather + append
    float g0 = gates_lds[b_*33 + jl_     ] + gxi;   // i
    float g1 = gates_lds[b_*33 +  8 + jl_] + gxf;   // f
    float g2 = gates_lds[b_*33 + 16 + jl_] + gxg;   // g
    float g3 = gates_lds[b_*33 + 24 + jl_] + gxo;   // o
    float ig = sigmf(g0), fg = sigmf(g1), gg = tanhff(g2), og = sigmf(g3);
    creg = fg*creg + ig*gg;
    float hn = og * tanhff(creg);
    float mt = 0.f;
    #pragma unroll
    for (int l = 0; l < 5; ++l){
      float w = wt_lds[b_*5 + l];
      int  id = idx_lds[b_*5 + l];
      mt += w * memf[(long)id*BH + b_*NH + jg_];    // own-thread data: L2-warm now
    }
    float ho = hn + mt;
    long eoff = (long)b_*NH + jg_;
    long eidx = (long)(t+1)*BH + eoff;
    memf[eidx] = ho;                                // mem append == h_seq (plain, own)
    unsigned short h0s = f2bf(ho);
    unsigned short h1s = f2bf(ho - bf2f(h0s));
    int ph = __shfl_xor((int)h0s, 1);
    int pm = __shfl_xor((int)h1s, 1);
    if ((jl_ & 1) == 0){                            // pack pair -> one u32 write-through store
      unsigned uh = (unsigned)h0s | (((unsigned)ph) << 16);
      unsigned um = (unsigned)h1s | (((unsigned)pm) << 16);
      __hip_atomic_store((unsigned*)hh  + (eidx>>1), uh, __ATOMIC_RELAXED, __HIP_MEMORY_SCOPE_AGENT);
      __hip_atomic_store((unsigned*)hmf + (eidx>>1), um, __ATOMIC_RELAXED, __HIP_MEMORY_SCOPE_AGENT);
    }
    mseq[(long)t*BH + eoff] = f2bf(mt);             // plain, consumed next kernel
    if (t == SEQ-1) dout[HF_OFF + eoff] = ho;       // h_f

    // s2 partial of the appended entry (t+1) -> write-through
    float v = tanhff(ho) * wt2;
    v += __shfl_xor(v, 1); v += __shfl_xor(v, 2); v += __shfl_xor(v, 4);
    if (jl_ == 0)
      __hip_atomic_store((unsigned*)(s2p + (long)(t+1)*2048 + b_*64 + g), __float_as_uint(v),
                         __ATOMIC_RELAXED, __HIP_MEMORY_SCOPE_AGENT);

    ++epoch;
    gbar(bar, g, epoch);
  }
  dout[CF_OFF + (long)b_*NH + jg_] = creg;          // c_f
}

// ---------------- phase 3: out = [h_seq; m_seq] @ fc_w^T + fc_b   (M=16384, N=512, K=1024)
__launch_bounds__(256)
__global__ void outgemm(const unsigned short* __restrict__ hh,
                        const unsigned short* __restrict__ mseq,
                        const unsigned short* __restrict__ fcwb,
                        const float* __restrict__ fcb,
                        float* __restrict__ out){
  const int tid = threadIdx.x;
  const int wave = tid >> 6, lane = tid & 63, quad = lane >> 4, ln = lane & 15;
  const int wgM = blockIdx.x;            // 256 tiles of 64 rows
  const int wgN = blockIdx.y;            // 8 tiles of 64 cols
  const int r = wgM*64 + wave*16 + ln;   // row (s*32+b); 16-row tiles never straddle s
  const int s = r >> 5, b = r & 31;
  const unsigned short* pa_h = hh   + (long)(s+1)*BH + (long)b*NH + quad*8;  // h_seq[s] = slot s+1
  const unsigned short* pa_m = mseq + (long)s*BH     + (long)b*NH + quad*8;
  const unsigned short* pb   = fcwb + (long)(wgN*64 + ln)*1024 + quad*8;
  f32x4 accs[4] = {{0,0,0,0},{0,0,0,0},{0,0,0,0},{0,0,0,0}};
  #pragma unroll 4
  for (int ki = 0; ki < 16; ++ki){       // h half (k < 512)
    bf16x8 a = *(const bf16x8*)(pa_h + ki*32);
    #pragma unroll
    for (int n = 0; n < 4; ++n){
      bf16x8 bb = *(const bf16x8*)(pb + (long)n*16*1024 + ki*32);
      accs[n] = __builtin_amdgcn_mfma_f32_16x16x32_bf16(a, bb, accs[n], 0,0,0);
    }
  }
  #pragma unroll 4
  for (int ki = 0; ki < 16; ++ki){       // m half (k >= 512)
    bf16x8 a = *(const bf16x8*)(pa_m + ki*32);
    #pragma unroll
    for (int n = 0; n < 4; ++n){
      bf16x8 bb = *(const bf16x8*)(pb + 512 + (long)n*16*1024 + ki*32);
      accs[n] = __builtin_amdgcn_mfma_f32_16x16x32_bf16(a, bb, accs[n], 0,0,0);
    }
  }
  #pragma unroll
  for (int n = 0; n < 4; ++n){
    int o = wgN*64 + n*16 + ln;
    float bias = fcb[o];
    #pragma unroll
    for (int rr = 0; rr < 4; ++rr){
      int row = wgM*64 + wave*16 + quad*4 + rr;
      out[(long)row*512 + o] = accs[n][rr] + bias;
    }
  }
}

extern "C" void kernel_launch(void* const* d_in, const int* in_sizes, int n_in,
                              void* d_out, int out_size, void* d_ws, size_t ws_size,
                              hipStream_t stream){
  (void)in_sizes; (void)n_in; (void)out_size; (void)ws_size;
  const float* x    = (const float*)d_in[0];
  const float* h0   = (const float*)d_in[1];
  const float* c0   = (const float*)d_in[2];
  const float* mem0 = (const float*)d_in[3];
  const float* wih  = (const float*)d_in[4];
  const float* whh  = (const float*)d_in[5];
  const float* bih  = (const float*)d_in[6];
  const float* bhh  = (const float*)d_in[7];
  const float* wt   = (const float*)d_in[8];
  const float* fcw  = (const float*)d_in[9];
  const float* fcb  = (const float*)d_in[10];
  float* out = (float*)d_out;
  char* ws = (char*)d_ws;

  unsigned short* x0   = (unsigned short*)(ws + X0_OFF);
  unsigned short* x1   = (unsigned short*)(ws + X1_OFF);
  unsigned short* wi0  = (unsigned short*)(ws + WI0_OFF);
  unsigned short* wi1  = (unsigned short*)(ws + WI1_OFF);
  unsigned short* hh   = (unsigned short*)(ws + HH_OFF);
  unsigned short* hmf  = (unsigned short*)(ws + HMF_OFF);
  unsigned short* mseq = (unsigned short*)(ws + MSEQ_OFF);
  unsigned short* fcwb = (unsigned short*)(ws + FCW_OFF);
  float*          s2p  = (float*)(ws + S2P_OFF);
  unsigned*       bar  = (unsigned*)(ws + BAR_OFF);
  float*          gx   = (float*)(ws + GX_OFF);

  phase0<<<32768, 256, 0, stream>>>(x, h0, mem0, fcw, wih,
                                    x0, x1, wi0, wi1,
                                    hh, hmf, fcwb, out + MEM_OFF, bar);
  xgemm<<<dim3(256, 32), 256, 0, stream>>>(x0, x1, wi0, wi1, bih, bhh, gx);
  recurrent<<<NWG, 256, 0, stream>>>(hh, hmf, mseq, s2p, bar, out,
                                     gx, whh, wt, c0);
  outgemm<<<dim3(256, 8), 256, 0, stream>>>(hh, mseq, fcwb, fcb, out);
}

// Round 4
// 3924.007 us; speedup vs baseline: 2.5728x; 1.4772x over previous
//
#include <hip/hip_runtime.h>

// Problem sizes
#define SEQ   512
#define NB    32
#define NH    512
#define BH    16384       // NB*NH
#define EPSF  1e-7f
#define NWG   64          // workgroups in persistent recurrent kernel

// d_out offsets (float elements): out(S,B,O), h_f(1,B,H), c_f(1,B,H), mem_f(513,B,H)
#define HF_OFF  8388608
#define CF_OFF  8404992
#define MEM_OFF 8421376

// ws offsets (bytes)
#define X0_OFF   0ul          // u16 [512][32][512]  bf16 hi of x
#define X1_OFF   16777216ul   // u16 mid of x
#define WI0_OFF  33554432ul   // u16 [2048][512] w_ih hi
#define WI1_OFF  35651584ul   // u16 mid
#define HH_OFF   37748736ul   // u16 [513][64g][32b][8c]  h hi  (slot0=h0, slot t+1=h_out_t)
#define HMF_OFF  54558720ul   // u16 [513][64g][32b][8c]  h mid
#define MSEQ_OFF 71368704ul   // u16 [512][32][512]  bf16(m_t)
#define FCW_OFF  88145920ul   // u16 [512][1024]     bf16(fc_w)
#define S2P_OFF  89194496ul   // f32 [513][64g][32b] per-WG score partials (write-once slots)
#define BAR_OFF  93396992ul   // u32 [64][32]        barrier slots, 128-B padded
#define GX_OFF   93405184ul   // f32 [512*32][2048]  precomputed x@w_ih^T + b_ih + b_hh

typedef __attribute__((ext_vector_type(8))) short bf16x8;
typedef __attribute__((ext_vector_type(4))) float f32x4;
typedef __attribute__((ext_vector_type(4))) int   i32x4;

__device__ __forceinline__ unsigned short f2bf(float f){
  unsigned u = __float_as_uint(f);
  unsigned r = (u + 0x7fffu + ((u >> 16) & 1u)) >> 16;   // RNE
  return (unsigned short)r;
}
__device__ __forceinline__ float bf2f(unsigned short h){
  return __uint_as_float(((unsigned)h) << 16);
}
__device__ __forceinline__ float sigmf(float x){ return 1.f/(1.f + __expf(-x)); }
__device__ __forceinline__ float tanhff(float x){
  x = fminf(20.f, fmaxf(-20.f, x));
  float e = __expf(-2.f*x);
  return (1.f - e)/(1.f + e);
}

// 16-B store that bypasses L1/L2 (write-through to LLC), line-contention-free
// when destinations are WG-exclusive.
__device__ __forceinline__ void store16_cc(void* p, i32x4 v){
  asm volatile("global_store_dwordx4 %0, %1, off sc0 sc1" :: "v"(p), "v"(v) : "memory");
}

// ---------------- phase 0: 2-way bf16 splits + init (zeroes barrier every launch)
__global__ void phase0(const float* __restrict__ x, const float* __restrict__ h0,
                       const float* __restrict__ mem0, const float* __restrict__ fcw,
                       const float* __restrict__ wih,
                       unsigned short* __restrict__ x0, unsigned short* __restrict__ x1,
                       unsigned short* __restrict__ wi0, unsigned short* __restrict__ wi1,
                       unsigned short* __restrict__ hh, unsigned short* __restrict__ hmf,
                       unsigned short* __restrict__ fcwb,
                       float* __restrict__ mem_row0, unsigned* __restrict__ bar){
  long i = (long)blockIdx.x * blockDim.x + threadIdx.x;
  if (i < (long)SEQ*BH){
    float v = x[i];
    unsigned short a = f2bf(v);
    x0[i]=a; x1[i]=f2bf(v - bf2f(a));
  }
  if (i < 2048*512){
    float v = wih[i];
    unsigned short a = f2bf(v);
    wi0[i]=a; wi1[i]=f2bf(v - bf2f(a));
  }
  if (i < 512*1024) fcwb[i] = f2bf(fcw[i]);
  if (i < BH){
    float h = h0[i];
    unsigned short a = f2bf(h);
    int b = (int)(i >> 9), col = (int)(i & 511);
    long d = (long)(col>>3)*256 + b*8 + (col&7);     // [g][b][c] layout, slot 0
    hh[d]=a; hmf[d]=f2bf(h - bf2f(a));
    mem_row0[i] = mem0[i];
  }
  if (i < 2048) bar[i] = 0u;                          // 64 slots x 128 B
}

// ---------------- phase 1: G_x = x @ w_ih^T + b_ih + b_hh  (3-term split MFMA)
// M=16384 (row = t*32+b), N=2048, K=512
__launch_bounds__(256)
__global__ void xgemm(const unsigned short* __restrict__ x0, const unsigned short* __restrict__ x1,
                      const unsigned short* __restrict__ wi0, const unsigned short* __restrict__ wi1,
                      const float* __restrict__ bih, const float* __restrict__ bhh,
                      float* __restrict__ gx){
  const int tid = threadIdx.x;
  const int wave = tid >> 6, lane = tid & 63, quad = lane >> 4, ln = lane & 15;
  const int rowb = blockIdx.x*64 + wave*16;
  const int colb = blockIdx.y*64;
  const long aoff = (long)(rowb + ln)*512 + quad*8;
  f32x4 acc[4] = {{0,0,0,0},{0,0,0,0},{0,0,0,0},{0,0,0,0}};
  #pragma unroll 4
  for (int ki = 0; ki < 16; ++ki){
    bf16x8 a0 = *(const bf16x8*)(x0 + aoff + ki*32);
    bf16x8 a1 = *(const bf16x8*)(x1 + aoff + ki*32);
    #pragma unroll
    for (int n = 0; n < 4; ++n){
      long bo = (long)(colb + n*16 + ln)*512 + quad*8 + ki*32;
      bf16x8 b0 = *(const bf16x8*)(wi0 + bo);
      bf16x8 b1 = *(const bf16x8*)(wi1 + bo);
      acc[n] = __builtin_amdgcn_mfma_f32_16x16x32_bf16(a0, b0, acc[n], 0,0,0);
      acc[n] = __builtin_amdgcn_mfma_f32_16x16x32_bf16(a0, b1, acc[n], 0,0,0);
      acc[n] = __builtin_amdgcn_mfma_f32_16x16x32_bf16(a1, b0, acc[n], 0,0,0);
    }
  }
  #pragma unroll
  for (int n = 0; n < 4; ++n){
    int col = colb + n*16 + ln;
    float bias = bih[col] + bhh[col];
    #pragma unroll
    for (int rr = 0; rr < 4; ++rr){
      int row = rowb + quad*4 + rr;
      gx[(long)row*2048 + col] = acc[n][rr] + bias;
    }
  }
}

// ---------------- phase 2: persistent recurrent kernel: 64 WGs x 256 threads
__launch_bounds__(256, 1)
__global__ void recurrent(unsigned short* __restrict__ hh,
                          unsigned short* __restrict__ hmf,
                          unsigned short* __restrict__ mseq,
                          float* __restrict__ s2p,
                          unsigned* __restrict__ bar,
                          float* __restrict__ dout,
                          const float* __restrict__ gx,
                          const float* __restrict__ whh,
                          const float* __restrict__ wt,
                          const float* __restrict__ c0){
  const int g    = blockIdx.x;           // WG owns hidden cols [g*8, g*8+8), all 4 gates
  const int tid  = threadIdx.x;
  const int wave = tid >> 6, lane = tid & 63, quad = lane >> 4, ln = lane & 15;
  const int mtile = wave & 1, ntile = wave >> 1;   // 32x32 tile = 2x2 of 16x16 per wave

  __shared__ float gates_lds[32*33];     // [b][c], padded
  __shared__ float wt_lds[32*5];
  __shared__ int   idx_lds[32*5];
  __shared__ unsigned hm_lds[256];       // packed hi|mid<<16 per (b,jl)
  __shared__ float s2_lds[32];

  // w_hh 2-split fragments in registers (hi+mid, 3-term scheme)
  bf16x8 fW0[16], fW1[16];
  {
    int cl   = ntile*16 + ln;            // local col 0..31; c = gate*8 + jloc
    int gate = cl >> 3, jl = cl & 7;
    long grow = (long)(gate*NH + g*8 + jl);
    const float* wh = whh + grow*NH;
    #pragma unroll
    for (int ki = 0; ki < 16; ++ki){
      int k0 = ki*32 + quad*8;
      bf16x8 a, b;
      #pragma unroll
      for (int e = 0; e < 8; ++e){
        float vh = wh[k0+e];
        unsigned short w0 = f2bf(vh);
        a[e] = (short)w0; b[e] = (short)f2bf(vh - bf2f(w0));
      }
      fW0[ki]=a; fW1[ki]=b;
    }
  }

  // elementwise ownership: thread <-> (b, jloc)
  const int b_  = tid >> 3, jl_ = tid & 7;
  const int jg_ = g*8 + jl_;
  const float wt2 = wt[NH + jg_];        // memory half of w_t (h half cancels)
  float creg = c0[b_*NH + jg_];
  float* memf = dout + MEM_OFF;

  // s2 partial for entry 0 (= mem0), layout [513][64][32]
  {
    float v = tanhff(memf[b_*NH + jg_]) * wt2;
    v += __shfl_xor(v, 1); v += __shfl_xor(v, 2); v += __shfl_xor(v, 4);
    if (jl_ == 0)
      __hip_atomic_store((unsigned*)(s2p + g*32 + b_), __float_as_uint(v),
                         __ATOMIC_RELAXED, __HIP_MEMORY_SCOPE_AGENT);
  }

  // gx prefetch for t=0
  const float* gxr0 = gx + (long)b_*2048 + jg_;
  float gxi = gxr0[0], gxf = gxr0[512], gxg = gxr0[1024], gxo = gxr0[1536];

  // replicated incremental top-5 (wave0 lanes 0..31, lane = batch)
  float tv0=-3e38f,tv1=-3e38f,tv2=-3e38f,tv3=-3e38f,tv4=-3e38f;
  int   ti0=0,ti1=0,ti2=0,ti3=0,ti4=0;

  unsigned epoch = 1u;
  __syncthreads();
  if (tid == 0)
    __hip_atomic_store(&bar[g*32], epoch, __ATOMIC_RELAXED, __HIP_MEMORY_SCOPE_AGENT);
  if (tid < 64){
    while (true){
      unsigned v = __hip_atomic_load(&bar[tid*32], __ATOMIC_RELAXED, __HIP_MEMORY_SCOPE_AGENT);
      if (__all((int)(v >= epoch))) break;
    }
  }
  __syncthreads();

  const int arow = mtile*16 + ln;        // A-frag row (batch)

  #pragma unroll 1
  for (int t = 0; t < SEQ; ++t){
    // --- wave0: read s2p slot t, finalize score, top-5, emit sparse weights
    if (tid < 32){
      const float* sp = s2p + (long)t*2048 + tid;
      float s0=0.f,s1=0.f,s2v=0.f,s3=0.f;
      #pragma unroll
      for (int q = 0; q < 64; q += 4){
        s0  += sp[(q  )*32];
        s1  += sp[(q+1)*32];
        s2v += sp[(q+2)*32];
        s3  += sp[(q+3)*32];
      }
      float s = (s0+s1) + (s2v+s3);      // fixed order → bit-identical across WGs
      if (t < 5){
        if      (t==0){tv0=s;ti0=0;}
        else if (t==1){tv1=s;ti1=1;}
        else if (t==2){tv2=s;ti2=2;}
        else if (t==3){tv3=s;ti3=3;}
        else          {tv4=s;ti4=4;}
      } else {
        float mn = fminf(fminf(fminf(tv0,tv1),fminf(tv2,tv3)),tv4);
        if (s > mn){
          if      (tv0==mn){tv0=s;ti0=t;}
          else if (tv1==mn){tv1=s;ti1=t;}
          else if (tv2==mn){tv2=s;ti2=t;}
          else if (tv3==mn){tv3=s;ti3=t;}
          else             {tv4=s;ti4=t;}
        }
      }
      int cnt = (t+1 < 5) ? (t+1) : 5;
      float mn = tv0;
      if (cnt>1) mn = fminf(mn, tv1);
      if (cnt>2) mn = fminf(mn, tv2);
      if (cnt>3) mn = fminf(mn, tv3);
      if (cnt>4) mn = fminf(mn, tv4);
      float thr = mn + EPSF;             // kth/min + eps; h-term cancels
      float w0 =            fmaxf(tv0-thr,0.f);
      float w1 = (cnt>1) ? fmaxf(tv1-thr,0.f) : 0.f;
      float w2 = (cnt>2) ? fmaxf(tv2-thr,0.f) : 0.f;
      float w3 = (cnt>3) ? fmaxf(tv3-thr,0.f) : 0.f;
      float w4 = (cnt>4) ? fmaxf(tv4-thr,0.f) : 0.f;
      float inv = 1.f/((w0+w1+w2+w3+w4) + EPSF);
      wt_lds[tid*5+0]=w0*inv; idx_lds[tid*5+0]=ti0;
      wt_lds[tid*5+1]=w1*inv; idx_lds[tid*5+1]=ti1;
      wt_lds[tid*5+2]=w2*inv; idx_lds[tid*5+2]=ti2;
      wt_lds[tid*5+3]=w3*inv; idx_lds[tid*5+3]=ti3;
      wt_lds[tid*5+4]=w4*inv; idx_lds[tid*5+4]=ti4;
    }

    // --- gates tile: h_t @ w_hh^T, 3-term split MFMA, two chains
    // A layout: element = t*BH + (ki*4+quad)*256 + row*8
    const unsigned short* p0 = hh  + (long)t*BH + quad*256 + arow*8;
    const unsigned short* p1 = hmf + (long)t*BH + quad*256 + arow*8;
    f32x4 acc0 = {0.f,0.f,0.f,0.f}, acc1 = {0.f,0.f,0.f,0.f};
    #pragma unroll
    for (int ki = 0; ki < 16; ++ki){
      bf16x8 aH = *(const bf16x8*)(p0 + ki*1024);
      bf16x8 aM = *(const bf16x8*)(p1 + ki*1024);
      acc0 = __builtin_amdgcn_mfma_f32_16x16x32_bf16(aH, fW0[ki], acc0, 0,0,0);
      acc1 = __builtin_amdgcn_mfma_f32_16x16x32_bf16(aH, fW1[ki], acc1, 0,0,0);
      if (ki & 1) acc1 = __builtin_amdgcn_mfma_f32_16x16x32_bf16(aM, fW0[ki], acc1, 0,0,0);
      else        acc0 = __builtin_amdgcn_mfma_f32_16x16x32_bf16(aM, fW0[ki], acc0, 0,0,0);
    }
    #pragma unroll
    for (int r = 0; r < 4; ++r){
      int brow = mtile*16 + quad*4 + r;  // C/D: row=quad*4+reg, col=lane&15
      gates_lds[brow*33 + ntile*16 + ln] = acc0[r] + acc1[r];
    }
    __syncthreads();

    // --- LSTM elementwise (gates = G_x[t] + h-path) + sparse gather + append
    float g0 = gates_lds[b_*33 + jl_     ] + gxi;   // i
    float g1 = gates_lds[b_*33 +  8 + jl_] + gxf;   // f
    float g2 = gates_lds[b_*33 + 16 + jl_] + gxg;   // g
    float g3 = gates_lds[b_*33 + 24 + jl_] + gxo;   // o
    float ig = sigmf(g0), fg = sigmf(g1), gg = tanhff(g2), og = sigmf(g3);
    creg = fg*creg + ig*gg;
    float hn = og * tanhff(creg);
    float mt = 0.f;
    #pragma unroll
    for (int l = 0; l < 5; ++l){
      float w = wt_lds[b_*5 + l];
      int  id = idx_lds[b_*5 + l];
      mt += w * memf[(long)id*BH + b_*NH + jg_];    // own-thread data, L1/L2 warm
    }
    float ho = hn + mt;
    long eoff = (long)b_*NH + jg_;
    memf[(long)(t+1)*BH + eoff] = ho;               // mem append == h_seq (plain, own)
    unsigned short h0s = f2bf(ho);
    unsigned short h1s = f2bf(ho - bf2f(h0s));
    hm_lds[b_*8 + jl_] = (unsigned)h0s | (((unsigned)h1s) << 16);
    mseq[(long)t*BH + eoff] = f2bf(mt);             // plain, consumed next kernel
    if (t == SEQ-1) dout[HF_OFF + eoff] = ho;       // h_f

    // s2 partial of the appended entry (t+1)
    {
      float v = tanhff(ho) * wt2;
      v += __shfl_xor(v, 1); v += __shfl_xor(v, 2); v += __shfl_xor(v, 4);
      if (jl_ == 0) s2_lds[b_] = v;
    }

    // gx prefetch for next step (completes during barrier wait)
    {
      int tn = (t+1 < SEQ) ? t+1 : t;
      const float* gxr = gx + ((long)tn*32 + b_)*2048 + jg_;
      gxi = gxr[0]; gxf = gxr[512]; gxg = gxr[1024]; gxo = gxr[1536];
    }

    // --- publish (wave0, coalesced 16-B line-exclusive stores) + barrier
    __syncthreads();                     // hm_lds/s2_lds visible
    if (tid < 32){
      int b = tid;
      unsigned q0 = hm_lds[b*8+0], q1 = hm_lds[b*8+1], q2 = hm_lds[b*8+2], q3 = hm_lds[b*8+3];
      unsigned q4 = hm_lds[b*8+4], q5 = hm_lds[b*8+5], q6 = hm_lds[b*8+6], q7 = hm_lds[b*8+7];
      i32x4 hi, mi;
      hi[0] = (int)((q0 & 0xffffu) | (q1 << 16));
      hi[1] = (int)((q2 & 0xffffu) | (q3 << 16));
      hi[2] = (int)((q4 & 0xffffu) | (q5 << 16));
      hi[3] = (int)((q6 & 0xffffu) | (q7 << 16));
      mi[0] = (int)((q0 >> 16) | (q1 & 0xffff0000u));
      mi[1] = (int)((q2 >> 16) | (q3 & 0xffff0000u));
      mi[2] = (int)((q4 >> 16) | (q5 & 0xffff0000u));
      mi[3] = (int)((q6 >> 16) | (q7 & 0xffff0000u));
      long d = (long)(t+1)*BH + g*256 + b*8;        // elements
      store16_cc(hh  + d, hi);
      store16_cc(hmf + d, mi);
    } else if (tid < 40){
      int q = tid - 32;
      f32x4 sv = *(const f32x4*)&s2_lds[q*4];
      store16_cc(s2p + (long)(t+1)*2048 + g*32 + q*4, __builtin_bit_cast(i32x4, sv));
    }
    __syncthreads();                     // wave0 store acks (vmcnt 0)
    ++epoch;
    if (tid == 0)
      __hip_atomic_store(&bar[g*32], epoch, __ATOMIC_RELAXED, __HIP_MEMORY_SCOPE_AGENT);
    if (tid < 64){
      while (true){
        unsigned v = __hip_atomic_load(&bar[tid*32], __ATOMIC_RELAXED, __HIP_MEMORY_SCOPE_AGENT);
        if (__all((int)(v >= epoch))) break;
      }
    }
    __syncthreads();
  }
  dout[CF_OFF + (long)b_*NH + jg_] = creg;          // c_f
}

// ---------------- phase 3: out = [h_seq; m_seq] @ fc_w^T + fc_b   (M=16384, N=512, K=1024)
__launch_bounds__(256)
__global__ void outgemm(const unsigned short* __restrict__ hh,
                        const unsigned short* __restrict__ mseq,
                        const unsigned short* __restrict__ fcwb,
                        const float* __restrict__ fcb,
                        float* __restrict__ out){
  const int tid = threadIdx.x;
  const int wave = tid >> 6, lane = tid & 63, quad = lane >> 4, ln = lane & 15;
  const int wgM = blockIdx.x;            // 256 tiles of 64 rows
  const int wgN = blockIdx.y;            // 8 tiles of 64 cols
  const int r = wgM*64 + wave*16 + ln;   // row (s*32+b); 16-row tiles never straddle s
  const int s = r >> 5, b = r & 31;
  // h_seq[s] = hh slot s+1, layout [g][b][8c]
  const unsigned short* pa_h = hh   + (long)(s+1)*BH + quad*256 + b*8;
  const unsigned short* pa_m = mseq + (long)s*BH     + (long)b*NH + quad*8;
  const unsigned short* pb   = fcwb + (long)(wgN*64 + ln)*1024 + quad*8;
  f32x4 accs[4] = {{0,0,0,0},{0,0,0,0},{0,0,0,0},{0,0,0,0}};
  #pragma unroll 4
  for (int ki = 0; ki < 16; ++ki){       // h half (k < 512)
    bf16x8 a = *(const bf16x8*)(pa_h + ki*1024);
    #pragma unroll
    for (int n = 0; n < 4; ++n){
      bf16x8 bb = *(const bf16x8*)(pb + (long)n*16*1024 + ki*32);
      accs[n] = __builtin_amdgcn_mfma_f32_16x16x32_bf16(a, bb, accs[n], 0,0,0);
    }
  }
  #pragma unroll 4
  for (int ki = 0; ki < 16; ++ki){       // m half (k >= 512)
    bf16x8 a = *(const bf16x8*)(pa_m + ki*32);
    #pragma unroll
    for (int n = 0; n < 4; ++n){
      bf16x8 bb = *(const bf16x8*)(pb + 512 + (long)n*16*1024 + ki*32);
      accs[n] = __builtin_amdgcn_mfma_f32_16x16x32_bf16(a, bb, accs[n], 0,0,0);
    }
  }
  #pragma unroll
  for (int n = 0; n < 4; ++n){
    int o = wgN*64 + n*16 + ln;
    float bias = fcb[o];
    #pragma unroll
    for (int rr = 0; rr < 4; ++rr){
      int row = wgM*64 + wave*16 + quad*4 + rr;
      out[(long)row*512 + o] = accs[n][rr] + bias;
    }
  }
}

extern "C" void kernel_launch(void* const* d_in, const int* in_sizes, int n_in,
                              void* d_out, int out_size, void* d_ws, size_t ws_size,
                              hipStream_t stream){
  (void)in_sizes; (void)n_in; (void)out_size; (void)ws_size;
  const float* x    = (const float*)d_in[0];
  const float* h0   = (const float*)d_in[1];
  const float* c0   = (const float*)d_in[2];
  const float* mem0 = (const float*)d_in[3];
  const float* wih  = (const float*)d_in[4];
  const float* whh  = (const float*)d_in[5];
  const float* bih  = (const float*)d_in[6];
  const float* bhh  = (const float*)d_in[7];
  const float* wt   = (const float*)d_in[8];
  const float* fcw  = (const float*)d_in[9];
  const float* fcb  = (const float*)d_in[10];
  float* out = (float*)d_out;
  char* ws = (char*)d_ws;

  unsigned short* x0   = (unsigned short*)(ws + X0_OFF);
  unsigned short* x1   = (unsigned short*)(ws + X1_OFF);
  unsigned short* wi0  = (unsigned short*)(ws + WI0_OFF);
  unsigned short* wi1  = (unsigned short*)(ws + WI1_OFF);
  unsigned short* hh   = (unsigned short*)(ws + HH_OFF);
  unsigned short* hmf  = (unsigned short*)(ws + HMF_OFF);
  unsigned short* mseq = (unsigned short*)(ws + MSEQ_OFF);
  unsigned short* fcwb = (unsigned short*)(ws + FCW_OFF);
  float*          s2p  = (float*)(ws + S2P_OFF);
  unsigned*       bar  = (unsigned*)(ws + BAR_OFF);
  float*          gx   = (float*)(ws + GX_OFF);

  phase0<<<32768, 256, 0, stream>>>(x, h0, mem0, fcw, wih,
                                    x0, x1, wi0, wi1,
                                    hh, hmf, fcwb, out + MEM_OFF, bar);
  xgemm<<<dim3(256, 32), 256, 0, stream>>>(x0, x1, wi0, wi1, bih, bhh, gx);
  recurrent<<<NWG, 256, 0, stream>>>(hh, hmf, mseq, s2p, bar, out,
                                     gx, whh, wt, c0);
  outgemm<<<dim3(256, 8), 256, 0, stream>>>(hh, mseq, fcwb, fcb, out);
}